// Round 4
// baseline (175.761 us; speedup 1.0000x reference)
//
#include <hip/hip_runtime.h>

// 19x19 box-sum, reflect pad 9, input (16,3,1024,1024) f32.
// V5: wave-autonomous streaming design. Each wave owns a 45-col output strip
// and walks a 128-row y-segment (146 input rows):
//   - 1 coalesced dword load per row (64 consecutive cols, reflect-x folded
//     into a per-lane offset computed once),
//   - horizontal 19-sum via DPP wave-prefix (VALU pipe, not LDS):
//       h[k] = Q[k+19] - Q[k], one ds_bpermute for the +19 pull,
//   - vertical 19-sum as a running window with a per-lane private LDS ring
//     (19 deep, lane reads only its own slot -> no barriers, no conflicts).
// No __syncthreads anywhere; fetch+store interleave continuously (the shape
// that reaches the 6.3 TB/s ceiling). LDS 9.7KB/block -> 32 waves/CU.

#define H     1024
#define W     1024
#define RAD   9
#define KW    19            // window
#define SOUT  45            // output cols per wave = 64 - KW
#define YSEG  128           // output rows per wave
#define TWALK (YSEG + 2*RAD)  // 146 input rows walked
#define NWAVE 2             // waves (strips) per block
#define NT    (NWAVE * 64)
#define NSTRIP 24           // 45*23 >= 1024; strip 23 is phantom (masked)

__device__ __forceinline__ int reflecti(int i, int n) {
    i = (i < 0) ? -i : i;
    return (i > n - 1) ? (2 * (n - 1) - i) : i;
}

// s + dpp(s); old=0 so masked/invalid lanes contribute 0 either way.
template<int CTRL, int RMASK>
__device__ __forceinline__ float dpp_add(float s) {
    int t = __builtin_amdgcn_update_dpp(0, __float_as_int(s), CTRL, RMASK, 0xf, true);
    return s + __int_as_float(t);
}

// wave64 inclusive prefix sum (canonical GCN scan: 4x row_shr + 2x row_bcast)
__device__ __forceinline__ float wave_prefix_incl(float x) {
    x = dpp_add<0x111, 0xf>(x);   // row_shr:1
    x = dpp_add<0x112, 0xf>(x);   // row_shr:2
    x = dpp_add<0x114, 0xf>(x);   // row_shr:4
    x = dpp_add<0x118, 0xf>(x);   // row_shr:8
    x = dpp_add<0x142, 0xa>(x);   // row_bcast:15 -> rows 1,3
    x = dpp_add<0x143, 0xc>(x);   // row_bcast:31 -> rows 2,3
    return x;
}

__global__ __launch_bounds__(NT, 8)
void boxsum19_kernel(const float* __restrict__ in, float* __restrict__ out) {
    __shared__ float ring[NWAVE * KW * 64];   // 2*19*64*4 = 9728 B

    const int tid  = threadIdx.x;
    const int lane = tid & 63;
    const int wid  = tid >> 6;

    const int strip = blockIdx.x * NWAVE + wid;   // 0..23 (23 = phantom)
    const int y0    = blockIdx.y * YSEG;
    const size_t img_off = (size_t)blockIdx.z * (size_t)(H * W);
    const float* __restrict__ inp  = in  + img_off;
    float* __restrict__       outp = out + img_off;

    // output col for this lane (valid when lane < SOUT and c < W)
    const int c = strip * SOUT + lane;
    const bool do_store = (lane < SOUT) && (c < W);

    // window col for this lane: wx0 + lane, wx0 = 45*strip - 10; reflect once.
    const int gx = reflecti(strip * SOUT - (RAD + 1) + lane, W);

    // per-lane private ring column
    float* ringp = &ring[wid * (KW * 64) + lane];

    float vsum = 0.f;
    int ws = 0;   // ring slot = t % 19

    int gy0 = reflecti(y0 - RAD, H);
    float e = inp[(size_t)gy0 * W + gx];

    for (int t = 0; t < TWALK; ++t) {
        // prefetch next row (t+1 == TWALK loads a valid reflected row; unused)
        const int gyn = reflecti(y0 - RAD + t + 1, H);
        const float en = inp[(size_t)gyn * W + gx];

        // horizontal 19-tap: h(k) = Q[k+19] - Q[k]   (k = lane)
        const float Q  = wave_prefix_incl(e);
        const float Qp = __int_as_float(
            __builtin_amdgcn_ds_bpermute((lane + KW) << 2, __float_as_int(Q)));
        const float h  = Qp - Q;   // junk for lane >= SOUT (masked at store)

        ringp[ws * 64] = h;
        vsum += h;

        if (t >= 2 * RAD) {
            if (do_store)
                outp[(size_t)(y0 + t - 2 * RAD) * W + c] = vsum;
            int rs = ws + 1; if (rs == KW) rs = 0;   // slot (t-18) % 19
            vsum -= ringp[rs * 64];
        }

        ++ws; if (ws == KW) ws = 0;
        e = en;
    }
}

extern "C" void kernel_launch(void* const* d_in, const int* in_sizes, int n_in,
                              void* d_out, int out_size, void* d_ws, size_t ws_size,
                              hipStream_t stream) {
    const float* in = (const float*)d_in[0];
    float* out = (float*)d_out;
    dim3 grid(NSTRIP / NWAVE, H / YSEG, 48);   // 12 x 8 x 48 = 4608 blocks
    boxsum19_kernel<<<grid, NT, 0, stream>>>(in, out);
}

// Round 5
// 124.919 us; speedup vs baseline: 1.4070x; 1.4070x over previous
//
#include <hip/hip_runtime.h>

// 19x19 box-sum, reflect pad 9, input (16,3,1024,1024) f32.
// V6: wave-autonomous streaming (V5 shape) with the latency serialization
// fixed:
//  - 19-deep rolling register prefetch (ea/eb slots, static indices via
//    19-chunked unroll): up to 19 row-loads in flight per wave (V5 had 1,
//    measured ~1800 cyc/row pure latency).
//  - vertical 19-window ring lives in REGISTERS (static slots), LDS = 0.
//  - full 64-col strips: 2 aligned coalesced row loads (a,b), horizontal
//    19-sum = P[k+25]-P[k+6] from two spliced wave-prefixes; disjoint index
//    ranges let one cndmask+bpermute serve each tap (2 bpermutes/row).
//  - dense aligned 256B stores (V5's 45-lane masked stores cost +10% write).

#define H    1024
#define W    1024
#define RAD  9
#define KW   19
#define YSEG 128
#define NT   256          // 4 independent waves per block, no barriers

__device__ __forceinline__ int reflecti(int i, int n) {
    i = (i < 0) ? -i : i;
    return (i > n - 1) ? (2 * (n - 1) - i) : i;
}

// s + dpp(s); old=0, bound_ctrl=1 -> out-of-range/unselected rows add 0.
template<int CTRL, int RMASK>
__device__ __forceinline__ float dpp_add(float s) {
    int t = __builtin_amdgcn_update_dpp(0, __float_as_int(s), CTRL, RMASK, 0xf, true);
    return s + __int_as_float(t);
}

// wave64 inclusive prefix sum (4x row_shr + 2x row_bcast) — HW-verified in V5
__device__ __forceinline__ float wave_prefix_incl(float x) {
    x = dpp_add<0x111, 0xf>(x);   // row_shr:1
    x = dpp_add<0x112, 0xf>(x);   // row_shr:2
    x = dpp_add<0x114, 0xf>(x);   // row_shr:4
    x = dpp_add<0x118, 0xf>(x);   // row_shr:8
    x = dpp_add<0x142, 0xa>(x);   // row_bcast:15 -> rows 1,3
    x = dpp_add<0x143, 0xc>(x);   // row_bcast:31 -> rows 2,3
    return x;
}

__global__ __launch_bounds__(NT, 6)
void boxsum19_kernel(const float* __restrict__ in, float* __restrict__ out) {
    const int lane = threadIdx.x & 63;
    const int wid  = threadIdx.x >> 6;

    const int x0 = blockIdx.x * 64;                    // 16 strips
    const int y0 = (blockIdx.y * 4 + wid) * YSEG;      // 8 y-segments
    const size_t img_off = (size_t)blockIdx.z * (size_t)(H * W);
    const float* __restrict__ inp  = in  + img_off;
    float* __restrict__       outp = out + img_off;

    // Row segment s[j] = x_reflect[x0-16+j], j=0..127: a holds j=0..63,
    // b holds j=64..127 (only j<=88 consumed). Reflect folded into offsets.
    const int gxa = reflecti(x0 - 16 + lane, W);
    const int gxb = reflecti(x0 + 48 + lane, W);
    // h[k] = P[k+25] - P[k+6] (19-tap around col x0+k), P = prefix of s.
    const int  i6   = ((lane + 6)  & 63) << 2;   // bpermute byte index
    const int  i25  = ((lane + 25) & 63) << 2;
    const bool c6   = lane < 6;    // merged-source: src[m] = m<6  ? Pb : Pa
    const bool c25  = lane < 25;   // merged-source: src[m] = m<25 ? Pb : Pa
    const int  outcol = x0 + lane;

    float ea[KW], eb[KW], ring[KW];
    float vsum = 0.f;

#define LOADROW(trow, slot) do {                                         \
        const int gy_ = reflecti(y0 - RAD + (trow), H);                  \
        const float* rp_ = inp + ((size_t)gy_ << 10);                    \
        ea[slot] = rp_[gxa];                                             \
        eb[slot] = rp_[gxb];                                             \
    } while (0)

#define HCOMP(slot, h) do {                                              \
        float Pa_ = wave_prefix_incl(ea[slot]);                          \
        float Pb_ = wave_prefix_incl(eb[slot]);                          \
        const float At_ = __int_as_float(                                \
            __builtin_amdgcn_readlane(__float_as_int(Pa_), 63));         \
        Pb_ += At_;                                                      \
        const float mq_ = c6  ? Pb_ : Pa_;                               \
        const float mr_ = c25 ? Pb_ : Pa_;                               \
        const float q_ = __int_as_float(                                 \
            __builtin_amdgcn_ds_bpermute(i6,  __float_as_int(mq_)));     \
        const float r_ = __int_as_float(                                 \
            __builtin_amdgcn_ds_bpermute(i25, __float_as_int(mr_)));     \
        h = r_ - q_;                                                     \
    } while (0)

    // ---- initial loads: rows 0..18 into slots 0..18 ----
    #pragma unroll
    for (int j = 0; j < KW; ++j) LOADROW(j, j);

    // ---- fill: t=0..17, build ring + vsum; prefetch rows 19..36 ----
    #pragma unroll
    for (int j = 0; j < KW - 1; ++j) {
        float h; HCOMP(j, h);
        LOADROW(j + KW, j);          // after consume: anti-dep keeps order
        ring[j] = h;
        vsum += h;
    }

    // ---- main: t=18..131 (outputs 0..113), 6 chunks of 19 ----
    // slot(t) = t%19 = (18+j)%19 ; evicted slot (t+1)%19 = j  — both static.
    int t = KW - 1;
    for (int blk = 0; blk < 6; ++blk) {
        #pragma unroll
        for (int j = 0; j < KW; ++j) {
            const int slot = (KW - 1 + j) % KW;
            float h; HCOMP(slot, h);
            LOADROW(t + KW, slot);   // rolling prefetch (reflect keeps it valid)
            vsum += h;
            outp[(size_t)(y0 + t - (KW - 1)) * W + outcol] = vsum;
            vsum -= ring[j];
            ring[slot] = h;
            ++t;
        }
    }

    // ---- epilogue: t=132..145 (outputs 114..127), no prefetch ----
    #pragma unroll
    for (int j = 0; j < YSEG - 6 * KW; ++j) {   // 14 iters
        const int slot = (KW - 1 + j) % KW;
        float h; HCOMP(slot, h);
        vsum += h;
        outp[(size_t)(y0 + t - (KW - 1)) * W + outcol] = vsum;
        vsum -= ring[j];
        ring[slot] = h;
        ++t;
    }

#undef LOADROW
#undef HCOMP
}

extern "C" void kernel_launch(void* const* d_in, const int* in_sizes, int n_in,
                              void* d_out, int out_size, void* d_ws, size_t ws_size,
                              hipStream_t stream) {
    const float* in = (const float*)d_in[0];
    float* out = (float*)d_out;
    dim3 grid(16, 2, 48);   // 16 strips x (8 ysegs / 4 waves) x 48 images
    boxsum19_kernel<<<grid, NT, 0, stream>>>(in, out);
}

// Round 6
// 93.789 us; speedup vs baseline: 1.8740x; 1.3319x over previous
//
#include <hip/hip_runtime.h>

// 19x19 box-sum, reflect pad 9, input (16,3,1024,1024) f32.
// V7 = V6 (wave-autonomous streaming, 19-deep rolling register prefetch,
// register vertical ring, DPP wave-prefix horizontal) with V6's measured
// defects fixed:
//  - launch_bounds(256,4): 128-VGPR budget. V6's (256,6)=85 spilled the
//    57-float pipeline (VGPR_Count=40, WRITE +30MB scratch) -> prefetch dead.
//  - eb row-load masked to lane<25: only Pb[0..24] is ever consumed by the
//    splice (bpermute wrap); raw x-fetch 128->89 cols per 64 outputs.
//  - XCD-chunked swizzle (1536 blocks = 8 XCDs x 192): each XCD owns 6 whole
//    images so x/y-halo re-reads hit its own L2.

#define H    1024
#define W    1024
#define RAD  9
#define KW   19
#define YSEG 128
#define NT   256          // 4 independent waves per block, no barriers

__device__ __forceinline__ int reflecti(int i, int n) {
    i = (i < 0) ? -i : i;
    return (i > n - 1) ? (2 * (n - 1) - i) : i;
}

// s + dpp(s); old=0, bound_ctrl=1 -> out-of-range/unselected rows add 0.
template<int CTRL, int RMASK>
__device__ __forceinline__ float dpp_add(float s) {
    int t = __builtin_amdgcn_update_dpp(0, __float_as_int(s), CTRL, RMASK, 0xf, true);
    return s + __int_as_float(t);
}

// wave64 inclusive prefix sum (4x row_shr + 2x row_bcast) — HW-verified V5/V6
__device__ __forceinline__ float wave_prefix_incl(float x) {
    x = dpp_add<0x111, 0xf>(x);   // row_shr:1
    x = dpp_add<0x112, 0xf>(x);   // row_shr:2
    x = dpp_add<0x114, 0xf>(x);   // row_shr:4
    x = dpp_add<0x118, 0xf>(x);   // row_shr:8
    x = dpp_add<0x142, 0xa>(x);   // row_bcast:15 -> rows 1,3
    x = dpp_add<0x143, 0xc>(x);   // row_bcast:31 -> rows 2,3
    return x;
}

__global__ __launch_bounds__(NT, 4)
void boxsum19_kernel(const float* __restrict__ in, float* __restrict__ out) {
    const int lane = threadIdx.x & 63;
    const int wid  = threadIdx.x >> 6;

    // XCD-chunked bijective swizzle: flat 0..1535 -> XCD k owns images 6k..6k+5
    const int flat  = blockIdx.x;
    const int wg    = (flat & 7) * 192 + (flat >> 3);
    const int img   = wg >> 5;            // 0..47
    const int rem   = wg & 31;
    const int by    = rem >> 4;           // 0..1
    const int strip = rem & 15;           // 0..15

    const int x0 = strip * 64;
    const int y0 = (by * 4 + wid) * YSEG;
    const size_t img_off = (size_t)img * (size_t)(H * W);
    const float* __restrict__ inp  = in  + img_off;
    float* __restrict__       outp = out + img_off;

    // Row segment s[j] = x_reflect[x0-16+j]: a = j 0..63, b = j 64..88
    // (only lanes 0..24 of b are consumed by the splice). Reflect folded in.
    const int gxa = reflecti(x0 - 16 + lane, W);
    const int gxb = reflecti(x0 + 48 + lane, W);
    const bool ld_b = (lane < 25);
    // h[k] = P[k+25] - P[k+6] (19-tap around col x0+k), P = spliced prefix.
    const int  i6   = ((lane + 6)  & 63) << 2;   // bpermute byte index
    const int  i25  = ((lane + 25) & 63) << 2;
    const bool c6   = lane < 6;    // merged-source: src[m] = m<6  ? Pb : Pa
    const bool c25  = lane < 25;   // merged-source: src[m] = m<25 ? Pb : Pa
    const int  outcol = x0 + lane;

    float ea[KW], eb[KW], ring[KW];
    float vsum = 0.f;

#define LOADROW(trow, slot) do {                                         \
        const int gy_ = reflecti(y0 - RAD + (trow), H);                  \
        const float* rp_ = inp + ((size_t)gy_ << 10);                    \
        ea[slot] = rp_[gxa];                                             \
        if (ld_b) eb[slot] = rp_[gxb];                                   \
    } while (0)

#define HCOMP(slot, h) do {                                              \
        float Pa_ = wave_prefix_incl(ea[slot]);                          \
        float Pb_ = wave_prefix_incl(eb[slot]);                          \
        const float At_ = __int_as_float(                                \
            __builtin_amdgcn_readlane(__float_as_int(Pa_), 63));         \
        Pb_ += At_;                                                      \
        const float mq_ = c6  ? Pb_ : Pa_;                               \
        const float mr_ = c25 ? Pb_ : Pa_;                               \
        const float q_ = __int_as_float(                                 \
            __builtin_amdgcn_ds_bpermute(i6,  __float_as_int(mq_)));     \
        const float r_ = __int_as_float(                                 \
            __builtin_amdgcn_ds_bpermute(i25, __float_as_int(mr_)));     \
        h = r_ - q_;                                                     \
    } while (0)

    // init eb so masked lanes hold a defined value (never consumed anyway)
    #pragma unroll
    for (int j = 0; j < KW; ++j) eb[j] = 0.f;

    // ---- initial loads: rows 0..18 into slots 0..18 ----
    #pragma unroll
    for (int j = 0; j < KW; ++j) LOADROW(j, j);

    // ---- fill: t=0..17, build ring + vsum; prefetch rows 19..36 ----
    #pragma unroll
    for (int j = 0; j < KW - 1; ++j) {
        float h; HCOMP(j, h);
        LOADROW(j + KW, j);          // after consume: anti-dep keeps order
        ring[j] = h;
        vsum += h;
    }

    // ---- main: t=18..131 (outputs 0..113), 6 chunks of 19 ----
    // slot(t) = t%19 = (18+j)%19 ; evicted slot (t+1)%19 = j  — both static.
    int t = KW - 1;
    for (int blk = 0; blk < 6; ++blk) {
        #pragma unroll
        for (int j = 0; j < KW; ++j) {
            const int slot = (KW - 1 + j) % KW;
            float h; HCOMP(slot, h);
            LOADROW(t + KW, slot);   // rolling prefetch (reflect keeps it valid)
            vsum += h;
            outp[(size_t)(y0 + t - (KW - 1)) * W + outcol] = vsum;
            vsum -= ring[j];
            ring[slot] = h;
            ++t;
        }
    }

    // ---- epilogue: t=132..145 (outputs 114..127), no prefetch ----
    #pragma unroll
    for (int j = 0; j < YSEG - 6 * KW; ++j) {   // 14 iters
        const int slot = (KW - 1 + j) % KW;
        float h; HCOMP(slot, h);
        vsum += h;
        outp[(size_t)(y0 + t - (KW - 1)) * W + outcol] = vsum;
        vsum -= ring[j];
        ring[slot] = h;
        ++t;
    }

#undef LOADROW
#undef HCOMP
}

extern "C" void kernel_launch(void* const* d_in, const int* in_sizes, int n_in,
                              void* d_out, int out_size, void* d_ws, size_t ws_size,
                              hipStream_t stream) {
    const float* in = (const float*)d_in[0];
    float* out = (float*)d_out;
    dim3 grid(16 * 2 * 48, 1, 1);   // flat 1536 blocks, XCD-swizzled in-kernel
    boxsum19_kernel<<<grid, NT, 0, stream>>>(in, out);
}

// Round 7
// 93.740 us; speedup vs baseline: 1.8750x; 1.0005x over previous
//
#include <hip/hip_runtime.h>

// 19x19 box-sum, reflect pad 9, input (16,3,1024,1024) f32.
// V8 = V7 (wave-autonomous streaming, 19-slot register prefetch, register
// vertical ring, DPP wave-prefix horizontal, XCD swizzle) + two fixes for
// V7's measured shallow pipeline (VGPR_Count=48 < 57-float arrays, waves
// ~90% stalled):
//  - amdgpu_waves_per_eu(4,5): V7's launch_bounds(256,4) only set a FLOOR;
//    the scheduler targeted 8 waves/EU (<=64 VGPR) and sank the prefetch
//    loads to ~4-deep. Capping max at 5 removes the incentive to shrink
//    below ~102 VGPRs -> the 19-deep load pipeline can stay hoisted.
//  - 1-ahead staging of the horizontal chain: step t finishes row t with
//    one subtract (h = rc - qc) and issues row t+1's prefix+bpermutes
//    (consumed next step) -> the ~250-cycle DPP/bpermute latency chain
//    overlaps a full step instead of serializing every step.
// Ring/vsum/slot indexing is byte-identical to harness-verified V7.

#define H    1024
#define W    1024
#define RAD  9
#define KW   19
#define YSEG 128
#define NT   256          // 4 independent waves per block, no barriers

__device__ __forceinline__ int reflecti(int i, int n) {
    i = (i < 0) ? -i : i;
    return (i > n - 1) ? (2 * (n - 1) - i) : i;
}

// s + dpp(s); old=0, bound_ctrl=1 -> out-of-range/unselected rows add 0.
template<int CTRL, int RMASK>
__device__ __forceinline__ float dpp_add(float s) {
    int t = __builtin_amdgcn_update_dpp(0, __float_as_int(s), CTRL, RMASK, 0xf, true);
    return s + __int_as_float(t);
}

// wave64 inclusive prefix sum (4x row_shr + 2x row_bcast) — HW-verified V5-V7
__device__ __forceinline__ float wave_prefix_incl(float x) {
    x = dpp_add<0x111, 0xf>(x);   // row_shr:1
    x = dpp_add<0x112, 0xf>(x);   // row_shr:2
    x = dpp_add<0x114, 0xf>(x);   // row_shr:4
    x = dpp_add<0x118, 0xf>(x);   // row_shr:8
    x = dpp_add<0x142, 0xa>(x);   // row_bcast:15 -> rows 1,3
    x = dpp_add<0x143, 0xc>(x);   // row_bcast:31 -> rows 2,3
    return x;
}

__global__ __launch_bounds__(NT)
__attribute__((amdgpu_waves_per_eu(4, 5)))
void boxsum19_kernel(const float* __restrict__ in, float* __restrict__ out) {
    const int lane = threadIdx.x & 63;
    const int wid  = threadIdx.x >> 6;

    // XCD-chunked bijective swizzle: flat 0..1535 -> XCD k owns images 6k..6k+5
    const int flat  = blockIdx.x;
    const int wg    = (flat & 7) * 192 + (flat >> 3);
    const int img   = wg >> 5;            // 0..47
    const int rem   = wg & 31;
    const int by    = rem >> 4;           // 0..1
    const int strip = rem & 15;           // 0..15

    const int x0 = strip * 64;
    const int y0 = (by * 4 + wid) * YSEG;
    const size_t img_off = (size_t)img * (size_t)(H * W);
    const float* __restrict__ inp  = in  + img_off;
    float* __restrict__       outp = out + img_off;

    // Row segment s[j] = x_reflect[x0-16+j]: a = j 0..63, b = j 64..88
    // (only lanes 0..24 of b are consumed by the splice). Reflect folded in.
    const int gxa = reflecti(x0 - 16 + lane, W);
    const int gxb = reflecti(x0 + 48 + lane, W);
    const bool ld_b = (lane < 25);
    // h[k] = P[k+25] - P[k+6] (19-tap around col x0+k), P = spliced prefix.
    const int  i6   = ((lane + 6)  & 63) << 2;   // bpermute byte index
    const int  i25  = ((lane + 25) & 63) << 2;
    const bool c6   = lane < 6;    // merged-source: src[m] = m<6  ? Pb : Pa
    const bool c25  = lane < 25;   // merged-source: src[m] = m<25 ? Pb : Pa
    const int  outcol = x0 + lane;

    float ea[KW], eb[KW], ring[KW];
    float vsum = 0.f;

#define LOADROW(trow, slot) do {                                         \
        const int gy_ = reflecti(y0 - RAD + (trow), H);                  \
        const float* rp_ = inp + ((size_t)gy_ << 10);                    \
        ea[slot] = rp_[gxa];                                             \
        if (ld_b) eb[slot] = rp_[gxb];                                   \
    } while (0)

// issue the horizontal chain for a row: prefix + splice + 2 bpermutes.
// q/r are consumed by the NEXT step (h = r - q) -> latency overlapped.
#define HSTART(slot, q, r) do {                                          \
        float Pa_ = wave_prefix_incl(ea[slot]);                          \
        float Pb_ = wave_prefix_incl(eb[slot]);                          \
        const float At_ = __int_as_float(                                \
            __builtin_amdgcn_readlane(__float_as_int(Pa_), 63));         \
        Pb_ += At_;                                                      \
        const float mq_ = c6  ? Pb_ : Pa_;                               \
        const float mr_ = c25 ? Pb_ : Pa_;                               \
        q = __int_as_float(                                              \
            __builtin_amdgcn_ds_bpermute(i6,  __float_as_int(mq_)));     \
        r = __int_as_float(                                              \
            __builtin_amdgcn_ds_bpermute(i25, __float_as_int(mr_)));     \
    } while (0)

    // init eb so masked lanes hold a defined value (never consumed anyway)
    #pragma unroll
    for (int j = 0; j < KW; ++j) eb[j] = 0.f;

    // ---- initial loads: rows 0..18 into slots 0..18 ----
    #pragma unroll
    for (int j = 0; j < KW; ++j) LOADROW(j, j);

    // ---- fill: rows 0..17 -> ring/vsum; prefetch rows 19..36 ----
    #pragma unroll
    for (int j = 0; j < KW - 1; ++j) {
        float q_, r_; HSTART(j, q_, r_);
        const float h = r_ - q_;
        LOADROW(j + KW, j);          // after consume: anti-dep keeps order
        ring[j] = h;
        vsum += h;
    }

    float qc, rc;
    HSTART(18, qc, rc);              // stage row 18 (slot 18)

    // ---- main: t=18..131 (outputs 0..113), 6 chunks of 19 ----
    // slot(t) = (18+j)%19 ; slot(t+1) = j ; evicted ring entry = ring[j].
    int t = KW - 1;
    for (int blk = 0; blk < 6; ++blk) {
        #pragma unroll
        for (int j = 0; j < KW; ++j) {
            const int slot = (KW - 1 + j) % KW;
            const float h = rc - qc;     // finish row t (staged last step)
            HSTART(j, qc, rc);           // stage row t+1 (lives in slot j)
            LOADROW(t + KW, slot);       // prefetch row t+19 into freed slot
            vsum += h;
            outp[(size_t)(y0 + t - (KW - 1)) * W + outcol] = vsum;
            vsum -= ring[j];
            ring[slot] = h;
            ++t;
        }
    }

    // ---- epilogue: t=132..145 (outputs 114..127), no prefetch ----
    #pragma unroll
    for (int j = 0; j < YSEG - 6 * KW; ++j) {   // 14 iters
        const int slot = (KW - 1 + j) % KW;
        const float h = rc - qc;
        if (j < YSEG - 6 * KW - 1) {            // stage t+1 (slot j) if any
            HSTART(j, qc, rc);
        }
        vsum += h;
        outp[(size_t)(y0 + t - (KW - 1)) * W + outcol] = vsum;
        vsum -= ring[j];
        ring[slot] = h;
        ++t;
    }

#undef LOADROW
#undef HSTART
}

extern "C" void kernel_launch(void* const* d_in, const int* in_sizes, int n_in,
                              void* d_out, int out_size, void* d_ws, size_t ws_size,
                              hipStream_t stream) {
    const float* in = (const float*)d_in[0];
    float* out = (float*)d_out;
    dim3 grid(16 * 2 * 48, 1, 1);   // flat 1536 blocks, XCD-swizzled in-kernel
    boxsum19_kernel<<<grid, NT, 0, stream>>>(in, out);
}

// Round 8
// 88.705 us; speedup vs baseline: 1.9814x; 1.0568x over previous
//
#include <hip/hip_runtime.h>

// 19x19 box-sum, reflect pad 9, input (16,3,1024,1024) f32.
// V9 = V8 dataflow (wave-autonomous streaming, 19-slot prefetch ring,
// register vertical ring, DPP wave-prefix horizontal, 1-ahead h staging,
// XCD swizzle) with the load pipeline FORCED:
//  - loads are asm-volatile buffer_load_dword (SRSRC + per-lane voffset
//    computed once + SALU soffset per row): issue order PINNED -> the
//    scheduler can no longer sink prefetches next to their uses (V7/V8:
//    VGPR_Count=48 proved it collapsed the pipeline to ~4-deep).
//  - completion via counted s_waitcnt vmcnt(34) (+ sched_barrier(0), rule
//    #18) before each consume; single vmcnt(0) drain before the epilogue.
//    Safety: >=34 loads are issued after the consumed row's last load at
//    every step; interleaved stores only age it further.
//  - eb load unconditional with clamped column (same cache lines; no exec
//    masking around asm).

#define H    1024
#define W    1024
#define RAD  9
#define KW   19
#define YSEG 128
#define NT   256          // 4 independent waves per block, no barriers

typedef __attribute__((ext_vector_type(4))) unsigned int uint32x4;

__device__ __forceinline__ int reflecti(int i, int n) {
    i = (i < 0) ? -i : i;
    return (i > n - 1) ? (2 * (n - 1) - i) : i;
}

// s + dpp(s); old=0, bound_ctrl=1 -> out-of-range/unselected rows add 0.
template<int CTRL, int RMASK>
__device__ __forceinline__ float dpp_add(float s) {
    int t = __builtin_amdgcn_update_dpp(0, __float_as_int(s), CTRL, RMASK, 0xf, true);
    return s + __int_as_float(t);
}

// wave64 inclusive prefix sum (4x row_shr + 2x row_bcast) — HW-verified V5-V8
__device__ __forceinline__ float wave_prefix_incl(float x) {
    x = dpp_add<0x111, 0xf>(x);   // row_shr:1
    x = dpp_add<0x112, 0xf>(x);   // row_shr:2
    x = dpp_add<0x114, 0xf>(x);   // row_shr:4
    x = dpp_add<0x118, 0xf>(x);   // row_shr:8
    x = dpp_add<0x142, 0xa>(x);   // row_bcast:15 -> rows 1,3
    x = dpp_add<0x143, 0xc>(x);   // row_bcast:31 -> rows 2,3
    return x;
}

__global__ __launch_bounds__(NT, 4)
void boxsum19_kernel(const float* __restrict__ in, float* __restrict__ out) {
    const int lane = threadIdx.x & 63;
    const int wid  = threadIdx.x >> 6;

    // XCD-chunked bijective swizzle: flat 0..1535 -> XCD k owns images 6k..6k+5
    const int flat  = blockIdx.x;
    const int wg    = (flat & 7) * 192 + (flat >> 3);
    const int img   = wg >> 5;            // 0..47
    const int rem   = wg & 31;
    const int by    = rem >> 4;           // 0..1
    const int strip = rem & 15;           // 0..15

    const int x0  = strip * 64;
    const int y0r = __builtin_amdgcn_readfirstlane((by * 4 + wid) * YSEG); // SGPR
    const size_t img_off = (size_t)img * (size_t)(H * W);
    const float* __restrict__ inp  = in  + img_off;
    float* __restrict__       outp = out + img_off;

    // SRSRC for this image: base=inp, num_records=4MB, raw dword access.
    const unsigned long long ipu = (unsigned long long)(uintptr_t)inp;
    const uint32x4 srsrc = { (unsigned)ipu, (unsigned)(ipu >> 32),
                             (unsigned)(H * W * 4), 0x00020000u };

    // Row segment s[j] = x_reflect[x0-16+j]: a = j 0..63, b = j 64..88
    // (only Pb lanes 0..24 consumed by the splice; eb col clamped for 25..63
    //  -> same cache lines, no extra HBM traffic). Reflect folded in.
    const int gxa = reflecti(x0 - 16 + lane, W);
    const int gxb = reflecti(x0 + 48 + (lane < 25 ? lane : 24), W);
    const int voffa = gxa << 2;
    const int voffb = gxb << 2;
    // h[k] = P[k+25] - P[k+6] (19-tap around col x0+k), P = spliced prefix.
    const int  i6   = ((lane + 6)  & 63) << 2;   // bpermute byte index
    const int  i25  = ((lane + 25) & 63) << 2;
    const bool c6   = lane < 6;    // merged-source: src[m] = m<6  ? Pb : Pa
    const bool c25  = lane < 25;   // merged-source: src[m] = m<25 ? Pb : Pa
    const int  outcol = x0 + lane;

    float ea[KW], eb[KW], ring[KW];
    float vsum = 0.f;

// asm-pinned row load: soffset = gy*4096 (SALU), voff fixed per lane.
#define LOADROW(trow, slot) do {                                         \
        int gy_ = y0r - RAD + (trow);                                    \
        gy_ = (gy_ < 0) ? -gy_ : ((gy_ > H - 1) ? (2 * (H - 1) - gy_) : gy_); \
        const unsigned so_ = (unsigned)gy_ << 12;                        \
        asm volatile("buffer_load_dword %0, %1, %2, %3 offen"            \
            : "=v"(ea[slot]) : "v"(voffa), "s"(srsrc), "s"(so_));        \
        asm volatile("buffer_load_dword %0, %1, %2, %3 offen"            \
            : "=v"(eb[slot]) : "v"(voffb), "s"(srsrc), "s"(so_));        \
    } while (0)

// counted wait + scheduling fence (rule #18: fence consumer hoisting)
#define WAITVM(N) do {                                                   \
        asm volatile("s_waitcnt vmcnt(" #N ")");                         \
        __builtin_amdgcn_sched_barrier(0);                               \
    } while (0)

// issue the horizontal chain for a row: prefix + splice + 2 bpermutes.
// q/r are consumed by the NEXT step (h = r - q) -> latency overlapped.
#define HSTART(slot, q, r) do {                                          \
        float Pa_ = wave_prefix_incl(ea[slot]);                          \
        float Pb_ = wave_prefix_incl(eb[slot]);                          \
        const float At_ = __int_as_float(                                \
            __builtin_amdgcn_readlane(__float_as_int(Pa_), 63));         \
        Pb_ += At_;                                                      \
        const float mq_ = c6  ? Pb_ : Pa_;                               \
        const float mr_ = c25 ? Pb_ : Pa_;                               \
        q = __int_as_float(                                              \
            __builtin_amdgcn_ds_bpermute(i6,  __float_as_int(mq_)));     \
        r = __int_as_float(                                              \
            __builtin_amdgcn_ds_bpermute(i25, __float_as_int(mr_)));     \
    } while (0)

    // ---- prologue: issue rows 0..18 into slots 0..18 (38 loads) ----
    #pragma unroll
    for (int j = 0; j < KW; ++j) LOADROW(j, j);

    // ---- fill: rows 0..17 -> ring/vsum; prefetch rows 19..36 ----
    // After row j's 2nd load, 36 more loads are issued before this wait
    // -> vmcnt(34) guarantees row j arrived.
    #pragma unroll
    for (int j = 0; j < KW - 1; ++j) {
        WAITVM(34);
        float q_, r_; HSTART(j, q_, r_);
        const float h = r_ - q_;
        LOADROW(j + KW, j);
        ring[j] = h;
        vsum += h;
    }

    WAITVM(34);
    float qc, rc;
    HSTART(18, qc, rc);              // stage row 18 (slot 18)

    // ---- main: t=18..131 (outputs 0..113), 6 chunks of 19 ----
    // slot(t) = (18+j)%19 ; HSTART consumes row t+1 (slot j); evict ring[j].
    int t = KW - 1;
    for (int blk = 0; blk < 6; ++blk) {
        #pragma unroll
        for (int j = 0; j < KW; ++j) {
            const int slot = (KW - 1 + j) % KW;
            WAITVM(34);                  // protects row t+1 (>=34 loads after it)
            const float h = rc - qc;     // finish row t (staged last step)
            HSTART(j, qc, rc);           // stage row t+1 (slot j)
            LOADROW(t + KW, slot);       // pinned prefetch of row t+19
            vsum += h;
            outp[(size_t)(y0r + t - (KW - 1)) * W + outcol] = vsum;
            vsum -= ring[j];
            ring[slot] = h;
            ++t;
        }
    }

    // ---- epilogue: t=132..145 (outputs 114..127), drain once ----
    WAITVM(0);
    #pragma unroll
    for (int j = 0; j < YSEG - 6 * KW; ++j) {   // 14 iters
        const int slot = (KW - 1 + j) % KW;
        const float h = rc - qc;
        if (j < YSEG - 6 * KW - 1) {
            HSTART(j, qc, rc);           // stage row t+1 (slot j)
        }
        vsum += h;
        outp[(size_t)(y0r + t - (KW - 1)) * W + outcol] = vsum;
        vsum -= ring[j];
        ring[slot] = h;
        ++t;
    }

#undef LOADROW
#undef WAITVM
#undef HSTART
}

extern "C" void kernel_launch(void* const* d_in, const int* in_sizes, int n_in,
                              void* d_out, int out_size, void* d_ws, size_t ws_size,
                              hipStream_t stream) {
    const float* in = (const float*)d_in[0];
    float* out = (float*)d_out;
    dim3 grid(16 * 2 * 48, 1, 1);   // flat 1536 blocks, XCD-swizzled in-kernel
    boxsum19_kernel<<<grid, NT, 0, stream>>>(in, out);
}

// Round 9
// 87.909 us; speedup vs baseline: 1.9994x; 1.0091x over previous
//
#include <hip/hip_runtime.h>

// 19x19 box-sum, reflect pad 9, input (16,3,1024,1024) f32.
// V10 = V9 (asm-pinned buffer_loads, counted vmcnt, register rings, DPP
// wave-prefix horizontal, 1-ahead staging, XCD swizzle) restructured to
// PAIR-STEPS: 2 rows per step.
//  - two independent DPP/bpermute chains per step interleave -> the
//    ~150-200cy serial chain latency (V9's per-step stall) is half-hidden.
//  - half the s_waitcnt/sched_barrier step boundaries.
//  - ring depth 19 -> 20 slots (pair-friendly modulo); prologue = rows
//    0..19 (40 loads in flight); steady state WAITVM(36) completes exactly
//    the consumed pair. Loads cover rows 0..145 exactly (V9 overshot to 150).
//  - all ring/ea/eb indices are j-static inside unrolled chunks (rule #20).

#define H    1024
#define W    1024
#define RAD  9
#define KW   19
#define RING 20
#define YSEG 128
#define NT   256          // 4 independent waves per block, no barriers

typedef __attribute__((ext_vector_type(4))) unsigned int uint32x4;

__device__ __forceinline__ int reflecti(int i, int n) {
    i = (i < 0) ? -i : i;
    return (i > n - 1) ? (2 * (n - 1) - i) : i;
}

// s + dpp(s); old=0, bound_ctrl=1 -> out-of-range/unselected rows add 0.
template<int CTRL, int RMASK>
__device__ __forceinline__ float dpp_add(float s) {
    int t = __builtin_amdgcn_update_dpp(0, __float_as_int(s), CTRL, RMASK, 0xf, true);
    return s + __int_as_float(t);
}

// wave64 inclusive prefix sum (4x row_shr + 2x row_bcast) — HW-verified V5-V9
__device__ __forceinline__ float wave_prefix_incl(float x) {
    x = dpp_add<0x111, 0xf>(x);   // row_shr:1
    x = dpp_add<0x112, 0xf>(x);   // row_shr:2
    x = dpp_add<0x114, 0xf>(x);   // row_shr:4
    x = dpp_add<0x118, 0xf>(x);   // row_shr:8
    x = dpp_add<0x142, 0xa>(x);   // row_bcast:15 -> rows 1,3
    x = dpp_add<0x143, 0xc>(x);   // row_bcast:31 -> rows 2,3
    return x;
}

__global__ __launch_bounds__(NT, 4)
void boxsum19_kernel(const float* __restrict__ in, float* __restrict__ out) {
    const int lane = threadIdx.x & 63;
    const int wid  = threadIdx.x >> 6;

    // XCD-chunked bijective swizzle: flat 0..1535 -> XCD k owns images 6k..6k+5
    const int flat  = blockIdx.x;
    const int wg    = (flat & 7) * 192 + (flat >> 3);
    const int img   = wg >> 5;            // 0..47
    const int rem   = wg & 31;
    const int by    = rem >> 4;           // 0..1
    const int strip = rem & 15;           // 0..15

    const int x0  = strip * 64;
    const int y0r = __builtin_amdgcn_readfirstlane((by * 4 + wid) * YSEG); // SGPR
    const size_t img_off = (size_t)img * (size_t)(H * W);
    const float* __restrict__ inp  = in  + img_off;
    float* __restrict__       outp = out + img_off;

    // SRSRC for this image: base=inp, num_records=4MB, raw dword access.
    const unsigned long long ipu = (unsigned long long)(uintptr_t)inp;
    const uint32x4 srsrc = { (unsigned)ipu, (unsigned)(ipu >> 32),
                             (unsigned)(H * W * 4), 0x00020000u };

    // Row segment s[j] = x_reflect[x0-16+j]: a = j 0..63, b = j 64..88
    // (only Pb lanes 0..24 consumed; eb col clamped for lanes 25..63 ->
    //  same cache lines). Reflect folded into per-lane voffsets (once).
    const int gxa = reflecti(x0 - 16 + lane, W);
    const int gxb = reflecti(x0 + 48 + (lane < 25 ? lane : 24), W);
    const int voffa = gxa << 2;
    const int voffb = gxb << 2;
    // h[k] = P[k+25] - P[k+6] (19-tap around col x0+k), P = spliced prefix.
    const int  i6   = ((lane + 6)  & 63) << 2;   // bpermute byte index
    const int  i25  = ((lane + 25) & 63) << 2;
    const bool c6   = lane < 6;    // merged-source: src[m] = m<6  ? Pb : Pa
    const bool c25  = lane < 25;   // merged-source: src[m] = m<25 ? Pb : Pa
    const int  outcol = x0 + lane;

    float ea[RING], eb[RING], ring[RING];
    float vsum = 0.f;

// asm-pinned row load: soffset = gy*4096 (SALU), voff fixed per lane.
#define LOADROW(trow, slot) do {                                         \
        int gy_ = y0r - RAD + (trow);                                    \
        gy_ = (gy_ < 0) ? -gy_ : ((gy_ > H - 1) ? (2 * (H - 1) - gy_) : gy_); \
        const unsigned so_ = (unsigned)gy_ << 12;                        \
        asm volatile("buffer_load_dword %0, %1, %2, %3 offen"            \
            : "=v"(ea[slot]) : "v"(voffa), "s"(srsrc), "s"(so_));        \
        asm volatile("buffer_load_dword %0, %1, %2, %3 offen"            \
            : "=v"(eb[slot]) : "v"(voffb), "s"(srsrc), "s"(so_));        \
    } while (0)

// counted wait + scheduling fence (rule #18: fence consumer hoisting)
#define WAITVM(N) do {                                                   \
        asm volatile("s_waitcnt vmcnt(" #N ")");                         \
        __builtin_amdgcn_sched_barrier(0);                               \
    } while (0)

// issue the horizontal chain for a row: prefix + splice + 2 bpermutes.
// q/r are consumed at the NEXT step (h = r - q) -> latency overlapped.
#define HSTART(slot, q, r) do {                                          \
        float Pa_ = wave_prefix_incl(ea[slot]);                          \
        float Pb_ = wave_prefix_incl(eb[slot]);                          \
        const float At_ = __int_as_float(                                \
            __builtin_amdgcn_readlane(__float_as_int(Pa_), 63));         \
        Pb_ += At_;                                                      \
        const float mq_ = c6  ? Pb_ : Pa_;                               \
        const float mr_ = c25 ? Pb_ : Pa_;                               \
        q = __int_as_float(                                              \
            __builtin_amdgcn_ds_bpermute(i6,  __float_as_int(mq_)));     \
        r = __int_as_float(                                              \
            __builtin_amdgcn_ds_bpermute(i25, __float_as_int(mr_)));     \
    } while (0)

    // ---- prologue: issue rows 0..19 into slots 0..19 (40 loads) ----
    #pragma unroll
    for (int j = 0; j < RING; ++j) LOADROW(j, j);

    // ---- fill pairs p=0..8: rows 2p,2p+1 -> ring/vsum (no staging);
    //      prefetch rows 2p+20, 2p+21 into the just-consumed slots ----
    #pragma unroll
    for (int p = 0; p < 9; ++p) {
        WAITVM(36);
        float q0_, r0_, q1_, r1_;
        HSTART(2 * p,     q0_, r0_);
        HSTART(2 * p + 1, q1_, r1_);
        LOADROW(2 * p + 20, 2 * p);
        LOADROW(2 * p + 21, 2 * p + 1);
        const float h0 = r0_ - q0_;
        const float h1 = r1_ - q1_;
        ring[2 * p]     = h0;
        ring[2 * p + 1] = h1;
        vsum += h0;
        vsum += h1;
    }

    // ---- stage pair 9 (rows 18,19); prefetch rows 38,39 ----
    float qc0, rc0, qc1, rc1;
    WAITVM(36);
    HSTART(18, qc0, rc0);
    HSTART(19, qc1, rc1);
    LOADROW(38, 18);
    LOADROW(39, 19);

// main pair step: finish pair p-1 (rows t0-2,t0-1 -> outputs t0-20,t0-19),
// stage pair p (rows t0,t0+1 in slots s0,s1), prefetch pair p+10.
// Static indices: evict slots = s0,s1; ring-write slots = (s0+18)%20,(s1+18)%20.
#define MAINSTEP(t0_, s0_, s1_) do {                                     \
        WAITVM(36);                                                      \
        const float hp0 = rc0 - qc0;                                     \
        const float hp1 = rc1 - qc1;                                     \
        HSTART((s0_), qc0, rc0);                                         \
        HSTART((s1_), qc1, rc1);                                         \
        LOADROW((t0_) + 20, (s0_));                                      \
        LOADROW((t0_) + 21, (s1_));                                      \
        vsum += hp0;                                                     \
        outp[(size_t)(y0r + (t0_) - 20) * W + outcol] = vsum;            \
        vsum -= ring[(s0_)];                                             \
        ring[((s0_) + 18) % RING] = hp0;                                 \
        vsum += hp1;                                                     \
        outp[(size_t)(y0r + (t0_) - 19) * W + outcol] = vsum;            \
        vsum -= ring[(s1_)];                                             \
        ring[((s1_) + 18) % RING] = hp1;                                 \
    } while (0)

    // ---- main pairs p=10..59 (5 chunks of 10) + p=60..62 remainder ----
    for (int blk = 0; blk < 5; ++blk) {
        const int tb = 20 + 20 * blk;        // t0 of first pair in chunk
        #pragma unroll
        for (int j = 0; j < 10; ++j) {
            MAINSTEP(tb + 2 * j, 2 * j, 2 * j + 1);
        }
    }
    #pragma unroll
    for (int j = 0; j < 3; ++j) {            // p = 60..62, t0 = 120..124
        MAINSTEP(120 + 2 * j, 2 * j, 2 * j + 1);
    }

    // ---- drain: all rows loaded; pairs p=63..72 finish+stage, then final ----
    WAITVM(0);
    #pragma unroll
    for (int j = 0; j < 10; ++j) {
        // p = 63+j: finish pair p-1 (outputs 2p-20, 2p-19 = 106+2j, 107+2j)
        const float hp0 = rc0 - qc0;
        const float hp1 = rc1 - qc1;
        HSTART((6 + 2 * j) % RING, qc0, rc0);   // row 126+2j
        HSTART((7 + 2 * j) % RING, qc1, rc1);   // row 127+2j
        vsum += hp0;
        outp[(size_t)(y0r + 106 + 2 * j) * W + outcol] = vsum;
        vsum -= ring[(6 + 2 * j) % RING];
        ring[(4 + 2 * j) % RING] = hp0;
        vsum += hp1;
        outp[(size_t)(y0r + 107 + 2 * j) * W + outcol] = vsum;
        vsum -= ring[(7 + 2 * j) % RING];
        ring[(5 + 2 * j) % RING] = hp1;
    }
    {   // final finish: pair 72 (rows 144,145 -> outputs 126,127)
        const float hp0 = rc0 - qc0;
        const float hp1 = rc1 - qc1;
        vsum += hp0;
        outp[(size_t)(y0r + 126) * W + outcol] = vsum;
        vsum -= ring[6];                        // h[108] at slot 108%20=8? no: 126%20=6
        vsum += hp1;
        outp[(size_t)(y0r + 127) * W + outcol] = vsum;
    }

#undef LOADROW
#undef WAITVM
#undef HSTART
#undef MAINSTEP
}

extern "C" void kernel_launch(void* const* d_in, const int* in_sizes, int n_in,
                              void* d_out, int out_size, void* d_ws, size_t ws_size,
                              hipStream_t stream) {
    const float* in = (const float*)d_in[0];
    float* out = (float*)d_out;
    dim3 grid(16 * 2 * 48, 1, 1);   // flat 1536 blocks, XCD-swizzled in-kernel
    boxsum19_kernel<<<grid, NT, 0, stream>>>(in, out);
}

// Round 10
// 87.584 us; speedup vs baseline: 2.0068x; 1.0037x over previous
//
#include <hip/hip_runtime.h>

// 19x19 box-sum, reflect pad 9, input (16,3,1024,1024) f32.
// V10 = V9 (asm-pinned buffer_loads, counted vmcnt, register rings, DPP
// wave-prefix horizontal, 1-ahead staging, XCD swizzle) restructured to
// PAIR-STEPS: 2 rows per step.
//  - two independent DPP/bpermute chains per step interleave -> the
//    ~150-200cy serial chain latency (V9's per-step stall) is half-hidden.
//  - half the s_waitcnt/sched_barrier step boundaries.
//  - ring depth 19 -> 20 slots (pair-friendly modulo); prologue = rows
//    0..19 (40 loads in flight); steady state WAITVM(36) completes exactly
//    the consumed pair. Loads cover rows 0..145 exactly (V9 overshot to 150).
//  - all ring/ea/eb indices are j-static inside unrolled chunks (rule #20).

#define H    1024
#define W    1024
#define RAD  9
#define KW   19
#define RING 20
#define YSEG 128
#define NT   256          // 4 independent waves per block, no barriers

typedef __attribute__((ext_vector_type(4))) unsigned int uint32x4;

__device__ __forceinline__ int reflecti(int i, int n) {
    i = (i < 0) ? -i : i;
    return (i > n - 1) ? (2 * (n - 1) - i) : i;
}

// s + dpp(s); old=0, bound_ctrl=1 -> out-of-range/unselected rows add 0.
template<int CTRL, int RMASK>
__device__ __forceinline__ float dpp_add(float s) {
    int t = __builtin_amdgcn_update_dpp(0, __float_as_int(s), CTRL, RMASK, 0xf, true);
    return s + __int_as_float(t);
}

// wave64 inclusive prefix sum (4x row_shr + 2x row_bcast) — HW-verified V5-V9
__device__ __forceinline__ float wave_prefix_incl(float x) {
    x = dpp_add<0x111, 0xf>(x);   // row_shr:1
    x = dpp_add<0x112, 0xf>(x);   // row_shr:2
    x = dpp_add<0x114, 0xf>(x);   // row_shr:4
    x = dpp_add<0x118, 0xf>(x);   // row_shr:8
    x = dpp_add<0x142, 0xa>(x);   // row_bcast:15 -> rows 1,3
    x = dpp_add<0x143, 0xc>(x);   // row_bcast:31 -> rows 2,3
    return x;
}

__global__ __launch_bounds__(NT, 4)
void boxsum19_kernel(const float* __restrict__ in, float* __restrict__ out) {
    const int lane = threadIdx.x & 63;
    const int wid  = threadIdx.x >> 6;

    // XCD-chunked bijective swizzle: flat 0..1535 -> XCD k owns images 6k..6k+5
    const int flat  = blockIdx.x;
    const int wg    = (flat & 7) * 192 + (flat >> 3);
    const int img   = wg >> 5;            // 0..47
    const int rem   = wg & 31;
    const int by    = rem >> 4;           // 0..1
    const int strip = rem & 15;           // 0..15

    const int x0  = strip * 64;
    const int y0r = __builtin_amdgcn_readfirstlane((by * 4 + wid) * YSEG); // SGPR
    const size_t img_off = (size_t)img * (size_t)(H * W);
    const float* __restrict__ inp  = in  + img_off;
    float* __restrict__       outp = out + img_off;

    // SRSRC for this image: base=inp, num_records=4MB, raw dword access.
    const unsigned long long ipu = (unsigned long long)(uintptr_t)inp;
    const uint32x4 srsrc = { (unsigned)ipu, (unsigned)(ipu >> 32),
                             (unsigned)(H * W * 4), 0x00020000u };

    // Row segment s[j] = x_reflect[x0-16+j]: a = j 0..63, b = j 64..88
    // (only Pb lanes 0..24 consumed; eb col clamped for lanes 25..63 ->
    //  same cache lines). Reflect folded into per-lane voffsets (once).
    const int gxa = reflecti(x0 - 16 + lane, W);
    const int gxb = reflecti(x0 + 48 + (lane < 25 ? lane : 24), W);
    const int voffa = gxa << 2;
    const int voffb = gxb << 2;
    // h[k] = P[k+25] - P[k+6] (19-tap around col x0+k), P = spliced prefix.
    const int  i6   = ((lane + 6)  & 63) << 2;   // bpermute byte index
    const int  i25  = ((lane + 25) & 63) << 2;
    const bool c6   = lane < 6;    // merged-source: src[m] = m<6  ? Pb : Pa
    const bool c25  = lane < 25;   // merged-source: src[m] = m<25 ? Pb : Pa
    const int  outcol = x0 + lane;

    float ea[RING], eb[RING], ring[RING];
    float vsum = 0.f;

// asm-pinned row load: soffset = gy*4096 (SALU), voff fixed per lane.
#define LOADROW(trow, slot) do {                                         \
        int gy_ = y0r - RAD + (trow);                                    \
        gy_ = (gy_ < 0) ? -gy_ : ((gy_ > H - 1) ? (2 * (H - 1) - gy_) : gy_); \
        const unsigned so_ = (unsigned)gy_ << 12;                        \
        asm volatile("buffer_load_dword %0, %1, %2, %3 offen"            \
            : "=v"(ea[slot]) : "v"(voffa), "s"(srsrc), "s"(so_));        \
        asm volatile("buffer_load_dword %0, %1, %2, %3 offen"            \
            : "=v"(eb[slot]) : "v"(voffb), "s"(srsrc), "s"(so_));        \
    } while (0)

// counted wait + scheduling fence (rule #18: fence consumer hoisting)
#define WAITVM(N) do {                                                   \
        asm volatile("s_waitcnt vmcnt(" #N ")");                         \
        __builtin_amdgcn_sched_barrier(0);                               \
    } while (0)

// issue the horizontal chain for a row: prefix + splice + 2 bpermutes.
// q/r are consumed at the NEXT step (h = r - q) -> latency overlapped.
#define HSTART(slot, q, r) do {                                          \
        float Pa_ = wave_prefix_incl(ea[slot]);                          \
        float Pb_ = wave_prefix_incl(eb[slot]);                          \
        const float At_ = __int_as_float(                                \
            __builtin_amdgcn_readlane(__float_as_int(Pa_), 63));         \
        Pb_ += At_;                                                      \
        const float mq_ = c6  ? Pb_ : Pa_;                               \
        const float mr_ = c25 ? Pb_ : Pa_;                               \
        q = __int_as_float(                                              \
            __builtin_amdgcn_ds_bpermute(i6,  __float_as_int(mq_)));     \
        r = __int_as_float(                                              \
            __builtin_amdgcn_ds_bpermute(i25, __float_as_int(mr_)));     \
    } while (0)

    // ---- prologue: issue rows 0..19 into slots 0..19 (40 loads) ----
    #pragma unroll
    for (int j = 0; j < RING; ++j) LOADROW(j, j);

    // ---- fill pairs p=0..8: rows 2p,2p+1 -> ring/vsum (no staging);
    //      prefetch rows 2p+20, 2p+21 into the just-consumed slots ----
    #pragma unroll
    for (int p = 0; p < 9; ++p) {
        WAITVM(36);
        float q0_, r0_, q1_, r1_;
        HSTART(2 * p,     q0_, r0_);
        HSTART(2 * p + 1, q1_, r1_);
        LOADROW(2 * p + 20, 2 * p);
        LOADROW(2 * p + 21, 2 * p + 1);
        const float h0 = r0_ - q0_;
        const float h1 = r1_ - q1_;
        ring[2 * p]     = h0;
        ring[2 * p + 1] = h1;
        vsum += h0;
        vsum += h1;
    }

    // ---- stage pair 9 (rows 18,19); prefetch rows 38,39 ----
    float qc0, rc0, qc1, rc1;
    WAITVM(36);
    HSTART(18, qc0, rc0);
    HSTART(19, qc1, rc1);
    LOADROW(38, 18);
    LOADROW(39, 19);

// main pair step: finish pair p-1 (rows t0-2,t0-1 -> outputs t0-20,t0-19),
// stage pair p (rows t0,t0+1 in slots s0,s1), prefetch pair p+10.
// Static indices: evict slots = s0,s1; ring-write slots = (s0+18)%20,(s1+18)%20.
#define MAINSTEP(t0_, s0_, s1_) do {                                     \
        WAITVM(36);                                                      \
        const float hp0 = rc0 - qc0;                                     \
        const float hp1 = rc1 - qc1;                                     \
        HSTART((s0_), qc0, rc0);                                         \
        HSTART((s1_), qc1, rc1);                                         \
        LOADROW((t0_) + 20, (s0_));                                      \
        LOADROW((t0_) + 21, (s1_));                                      \
        vsum += hp0;                                                     \
        outp[(size_t)(y0r + (t0_) - 20) * W + outcol] = vsum;            \
        vsum -= ring[(s0_)];                                             \
        ring[((s0_) + 18) % RING] = hp0;                                 \
        vsum += hp1;                                                     \
        outp[(size_t)(y0r + (t0_) - 19) * W + outcol] = vsum;            \
        vsum -= ring[(s1_)];                                             \
        ring[((s1_) + 18) % RING] = hp1;                                 \
    } while (0)

    // ---- main pairs p=10..59 (5 chunks of 10) + p=60..62 remainder ----
    for (int blk = 0; blk < 5; ++blk) {
        const int tb = 20 + 20 * blk;        // t0 of first pair in chunk
        #pragma unroll
        for (int j = 0; j < 10; ++j) {
            MAINSTEP(tb + 2 * j, 2 * j, 2 * j + 1);
        }
    }
    #pragma unroll
    for (int j = 0; j < 3; ++j) {            // p = 60..62, t0 = 120..124
        MAINSTEP(120 + 2 * j, 2 * j, 2 * j + 1);
    }

    // ---- drain: all rows loaded; pairs p=63..72 finish+stage, then final ----
    WAITVM(0);
    #pragma unroll
    for (int j = 0; j < 10; ++j) {
        // p = 63+j: finish pair p-1 (outputs 2p-20, 2p-19 = 106+2j, 107+2j)
        const float hp0 = rc0 - qc0;
        const float hp1 = rc1 - qc1;
        HSTART((6 + 2 * j) % RING, qc0, rc0);   // row 126+2j
        HSTART((7 + 2 * j) % RING, qc1, rc1);   // row 127+2j
        vsum += hp0;
        outp[(size_t)(y0r + 106 + 2 * j) * W + outcol] = vsum;
        vsum -= ring[(6 + 2 * j) % RING];
        ring[(4 + 2 * j) % RING] = hp0;
        vsum += hp1;
        outp[(size_t)(y0r + 107 + 2 * j) * W + outcol] = vsum;
        vsum -= ring[(7 + 2 * j) % RING];
        ring[(5 + 2 * j) % RING] = hp1;
    }
    {   // final finish: pair 72 (rows 144,145 -> outputs 126,127)
        const float hp0 = rc0 - qc0;
        const float hp1 = rc1 - qc1;
        vsum += hp0;
        outp[(size_t)(y0r + 126) * W + outcol] = vsum;
        vsum -= ring[6];                        // h[108] at slot 108%20=8? no: 126%20=6
        vsum += hp1;
        outp[(size_t)(y0r + 127) * W + outcol] = vsum;
    }

#undef LOADROW
#undef WAITVM
#undef HSTART
#undef MAINSTEP
}

extern "C" void kernel_launch(void* const* d_in, const int* in_sizes, int n_in,
                              void* d_out, int out_size, void* d_ws, size_t ws_size,
                              hipStream_t stream) {
    const float* in = (const float*)d_in[0];
    float* out = (float*)d_out;
    dim3 grid(16 * 2 * 48, 1, 1);   // flat 1536 blocks, XCD-swizzled in-kernel
    boxsum19_kernel<<<grid, NT, 0, stream>>>(in, out);
}